// Round 8
// baseline (176.226 us; speedup 1.0000x reference)
//
#include <hip/hip_runtime.h>

#define B_    2
#define N_TOK 2048
#define C_    1024
#define H_    16
#define D_    64
#define M_    (B_*N_TOK)   // 4096
#define N3C   3072

typedef unsigned short u16;
typedef unsigned int   u32;

typedef __attribute__((ext_vector_type(8))) short bf16x8;
typedef __attribute__((ext_vector_type(4))) float f32x4;

__device__ __forceinline__ u16 f2bf(float f) {       // RNE
  u32 u = __float_as_uint(f);
  return (u16)((u + 0x7FFFu + ((u >> 16) & 1u)) >> 16);
}
__device__ __forceinline__ u16 f2bf_fast(float f) {  // round-half-up (P only)
  return (u16)((__float_as_uint(f) + 0x8000u) >> 16);
}

// async global->LDS, 16B/lane; LDS dest = wave-uniform base + lane*16
__device__ __forceinline__ void async16(const u16* g, u16* l) {
  __builtin_amdgcn_global_load_lds(
      (const __attribute__((address_space(1))) u32*)g,
      (__attribute__((address_space(3))) u32*)l, 16, 0, 0);
}

// ---------------- fused fp32 -> bf16 convert ----------------
__global__ void k_cvt(const float* __restrict__ x, const float* __restrict__ wq,
                      const float* __restrict__ wo,
                      u16* __restrict__ xb, u16* __restrict__ wqb, u16* __restrict__ wob) {
  size_t i = ((size_t)blockIdx.x * 256 + threadIdx.x) * 4;
  const size_t n0 = (size_t)M_ * C_;
  const size_t n1 = n0 + (size_t)N3C * C_;
  const float* s; u16* d;
  if (i < n0)      { s = x  + i;        d = xb  + i; }
  else if (i < n1) { s = wq + (i - n0); d = wqb + (i - n0); }
  else             { s = wo + (i - n1); d = wob + (i - n1); }
  float4 v = *(const float4*)s;
  *(ushort4*)d = make_ushort4(f2bf(v.x), f2bf(v.y), f2bf(v.z), f2bf(v.w));
}

// ---------------- GEMM1: qkv = x @ w_qkv^T + b   (BK=64, XOR-swizzled staging) ----------------
// Q -> [B,H,N,D] pre-scaled by 0.125*log2(e).
// K -> blocked [bh][t32:64][c:8][row:32][e:8], rows PERMUTED:
//      p(w) = ((w>>2)&1)*16 + ((w>>3)&3)*4 + (w&3)  (S^T C-layout == K=32 A-frag).
// V -> [b,h,d,N], key-chunks XOR-swizzled: chunk' = ((t>>3)&7) ^ (d&7).
__global__ __launch_bounds__(256, 3) void k_gemm_qkv(
    const u16* __restrict__ A, const u16* __restrict__ Bm,
    const float* __restrict__ bias,
    u16* __restrict__ qout, u16* __restrict__ kout, u16* __restrict__ vout)
{
  __shared__ u16 As[128*64];   // 16 KB
  __shared__ u16 Bs[128*64];   // 16 KB
  const int K = C_;
  int bm = blockIdx.x, bn = blockIdx.y;
  int tid = threadIdx.x;
  int lane = tid & 63, wave = tid >> 6;
  int wrow = (wave >> 1) * 64, wcol = (wave & 1) * 64;
  int qd = lane >> 4, ln = lane & 15;

  f32x4 zero = {0.f, 0.f, 0.f, 0.f};
  f32x4 acc[4][4];
  for (int i = 0; i < 4; i++) for (int j = 0; j < 4; j++) acc[i][j] = zero;

  const u16* Ab = A  + (size_t)bm * 128 * K;
  const u16* Bb = Bm + (size_t)bn * 128 * K;

  for (int k0 = 0; k0 < K; k0 += 64) {
    __syncthreads();
    for (int j = 0; j < 4; j++) {
      int slot = (wave*4 + j)*64 + lane;
      int r = slot >> 3, kc = slot & 7;
      int c = (kc ^ (r & 7)) * 8;
      async16(&Ab[(size_t)r * K + k0 + c], &As[(wave*4 + j) * 512]);
      async16(&Bb[(size_t)r * K + k0 + c], &Bs[(wave*4 + j) * 512]);
    }
    __syncthreads();
    for (int kk2 = 0; kk2 < 2; kk2++) {
      bf16x8 af[4], bfr[4];
      for (int mi = 0; mi < 4; mi++) {
        int row = wrow + mi*16 + ln;
        af[mi] = *(const bf16x8*)&As[(row*8 + ((kk2*4 + qd) ^ (ln & 7)))*8];
      }
      for (int ni = 0; ni < 4; ni++) {
        int row = wcol + ni*16 + ln;
        bfr[ni] = *(const bf16x8*)&Bs[(row*8 + ((kk2*4 + qd) ^ (ln & 7)))*8];
      }
      for (int mi = 0; mi < 4; mi++)
        for (int ni = 0; ni < 4; ni++)
          acc[mi][ni] = __builtin_amdgcn_mfma_f32_16x16x32_bf16(af[mi], bfr[ni], acc[mi][ni], 0, 0, 0);
    }
  }

  for (int ni = 0; ni < 4; ni++) {
    int nbase = bn*128 + wcol + ni*16 + ln;
    int three = nbase >> 10;        // wave-uniform
    int h = (nbase >> 6) & 15;
    int d = nbase & 63;
    float bv = bias[nbase];
    if (three == 2) {
      for (int mi = 0; mi < 4; mi++) {
        int row0 = bm*128 + wrow + mi*16 + qd*4;
        int b = row0 >> 11, t0 = row0 & 2047;
        int chunkp = ((t0 >> 3) & 7) ^ (d & 7);
        u16 tmp[4];
        for (int r = 0; r < 4; r++) tmp[r] = f2bf(acc[mi][ni][r] + bv);
        size_t off = ((size_t)(b*H_ + h)*D_ + d)*N_TOK + (t0 >> 6)*64 + chunkp*8 + (t0 & 7);
        *(ushort4*)&vout[off] = *(ushort4*)tmp;
      }
    } else if (three == 1) {
      int c = d >> 3, e = d & 7;
      for (int mi = 0; mi < 4; mi++) {
        for (int r = 0; r < 4; r++) {
          int row = bm*128 + wrow + mi*16 + qd*4 + r;
          int b = row >> 11, t = row & 2047;
          int t32 = t >> 5, w = t & 31;
          int p = ((w >> 2) & 1)*16 + ((w >> 3) & 3)*4 + (w & 3);
          kout[((size_t)(b*H_ + h)*64 + t32)*2048 + (c*32 + p)*8 + e] = f2bf(acc[mi][ni][r] + bv);
        }
      }
    } else {
      float sc = 0.18033688011f;  // 0.125*log2(e) folded into Q
      for (int mi = 0; mi < 4; mi++) {
        for (int r = 0; r < 4; r++) {
          int row = bm*128 + wrow + mi*16 + qd*4 + r;
          int b = row >> 11, t = row & 2047;
          qout[(((size_t)(b*H_ + h))*N_TOK + t)*D_ + d] = f2bf((acc[mi][ni][r] + bv) * sc);
        }
      }
    }
  }
}

// ---------------- flash attention: 128-key tiles, key-half x q-half wave split ----------------
// block = 128 q-rows, 4 waves; wave w: q-half (w>>1) [64 rows, mi=4] x key-half (w&1) [64 keys].
// 16 iterations of 128 keys; staging 32 KB shared; end-of-kernel partial combine via LDS.
__global__ __launch_bounds__(256, 2) void k_attn(
    const u16* __restrict__ Q, const u16* __restrict__ Kb, const u16* __restrict__ Vb,
    u16* __restrict__ Oa)   // [B*N][C] bf16
{
  __shared__ __align__(16) u16 smem[17408];  // 34 KB: 16K K + 16V staging (reused for O-combine) + 1K lsum
  u16* Ks = smem;             // [tile:4][c:8][row:32][e:8]  (4 x 32-key permuted tiles)
  u16* Vs = smem + 8192;      // [g:2][d:64][chunk':8][e:8]
  float* lsumL = (float*)(smem + 16384);  // [qh:2][mi:4][ln:16]

  int ord = blockIdx.x;                 // 0..511
  int xcd = ord & 7, kk = ord >> 3;
  int bh = xcd * 4 + (kk & 3);          // 4 heads per XCD -> K/V L2-resident
  int qt = kk >> 2;                     // 0..15
  int b = bh >> 4, h = bh & 15;
  int tid = threadIdx.x, lane = tid & 63, wave = tid >> 6;
  int qd = lane >> 4, ln = lane & 15;
  int qh = wave >> 1, kh = wave & 1;

  const u16* Qg  = Q  + ((size_t)bh * N_TOK + qt*128 + qh*64) * D_;
  const u16* KgB = Kb + (size_t)bh * 64 * 2048;
  const u16* Vg  = Vb + (size_t)bh * (size_t)D_ * N_TOK;

  bf16x8 qf[4][2];
  for (int mi = 0; mi < 4; mi++)
    for (int ks = 0; ks < 2; ks++)
      qf[mi][ks] = *(const bf16x8*)&Qg[(mi*16 + ln)*D_ + ks*32 + qd*8];

  f32x4 z = {0.f, 0.f, 0.f, 0.f};
  f32x4 oacc[4][4];
  float lsum[4] = {0.f, 0.f, 0.f, 0.f};
  for (int mi = 0; mi < 4; mi++) for (int di = 0; di < 4; di++) oacc[mi][di] = z;

  for (int kt = 0; kt < 16; kt++) {     // 128 keys per iteration
    __syncthreads();
    const u16* Kt = KgB + (size_t)kt * 8192;   // 4 consecutive 32-key blocked tiles
    for (int j = 0; j < 4; j++) {
      int cbase = wave*256 + j*64;
      async16(&Kt[(cbase + lane)*8], &Ks[cbase*8]);
    }
    for (int j = 0; j < 4; j++) {
      int cbase = wave*256 + j*64;
      int cl = cbase + lane;
      int g = cl >> 9, rem = cl & 511, d = rem >> 3, cp = rem & 7;
      async16(&Vg[(size_t)d*N_TOK + (kt*2 + g)*64 + cp*8], &Vs[cbase*8]);
    }
    __syncthreads();

    // wave's key-half: K tiles 2kh..2kh+1, V group g=kh
    bf16x8 kf[4][2];
    for (int nt = 0; nt < 4; nt++)
      for (int ksd = 0; ksd < 2; ksd++)
        kf[nt][ksd] = *(const bf16x8*)&Ks[(2*kh + (nt>>1))*2048 + ((ksd*4 + qd)*32 + (nt&1)*16 + ln)*8];
    bf16x8 vf[4][2];
    for (int di = 0; di < 4; di++)
      for (int hf = 0; hf < 2; hf++) {
        int d = di*16 + ln;
        vf[di][hf] = *(const bf16x8*)&Vs[kh*4096 + (d*8 + ((hf*4 + qd) ^ (ln & 7)))*8];
      }

    for (int mi = 0; mi < 4; mi++) {
      f32x4 sacc[4];
      for (int nt = 0; nt < 4; nt++) {
        sacc[nt] = z;
        for (int ksd = 0; ksd < 2; ksd++)
          sacc[nt] = __builtin_amdgcn_mfma_f32_16x16x32_bf16(kf[nt][ksd], qf[mi][ksd], sacc[nt], 0, 0, 0);
      }
      for (int hf = 0; hf < 2; hf++) {
        union { u16 s[8]; bf16x8 v; } pk;
        for (int nth = 0; nth < 2; nth++)
          for (int i = 0; i < 4; i++) {
            float e = __builtin_amdgcn_exp2f(sacc[hf*2 + nth][i]);
            lsum[mi] += e;
            pk.s[nth*4 + i] = f2bf_fast(e);
          }
        for (int di = 0; di < 4; di++)
          oacc[mi][di] = __builtin_amdgcn_mfma_f32_16x16x32_bf16(pk.v, vf[di][hf], oacc[mi][di], 0, 0, 0);
      }
    }
  }

  // qd-reduce lsum (each lane then holds l_partial(q=mi*16+ln) over wave's key-half)
  float lsr[4];
  for (int mi = 0; mi < 4; mi++) {
    float ls = lsum[mi];
    ls += __shfl_xor(ls, 16, 64);
    ls += __shfl_xor(ls, 32, 64);
    lsr[mi] = ls;
  }

  __syncthreads();   // staging dead; safe to reuse for O-combine
  if (kh == 1) {
    float* Rw = (float*)smem + qh * 4096;   // 16 KB region inside old staging
    for (int mi = 0; mi < 4; mi++)
      for (int di = 0; di < 4; di++)
        *(f32x4*)&Rw[(((mi*4 + di)*4 + qd)*16 + ln)*4] = oacc[mi][di];
    if (qd == 0)
      for (int mi = 0; mi < 4; mi++) lsumL[qh*64 + mi*16 + ln] = lsr[mi];
  }
  __syncthreads();
  if (kh == 0) {
    const float* Rp = (const float*)smem + qh * 4096;
    for (int mi = 0; mi < 4; mi++) {
      float rl[4];
      for (int r = 0; r < 4; r++) {
        float own = __shfl(lsr[mi], qd*4 + r, 64);
        float par = lsumL[qh*64 + mi*16 + qd*4 + r];
        rl[r] = 1.0f / (own + par);
      }
      for (int di = 0; di < 4; di++) {
        f32x4 osum = oacc[mi][di] + *(const f32x4*)&Rp[(((mi*4 + di)*4 + qd)*16 + ln)*4];
        for (int r = 0; r < 4; r++) {
          int t = qt*128 + qh*64 + mi*16 + qd*4 + r;
          Oa[((size_t)b*N_TOK + t)*C_ + h*D_ + di*16 + ln] = f2bf(osum[r] * rl[r]);
        }
      }
    }
  }
}

// ---------------- GEMM2: out = attn @ w_out^T + b_out (fp32), 64x128 tile, BK=64 ----------------
__global__ __launch_bounds__(256, 2) void k_gemm_out(
    const u16* __restrict__ A, const u16* __restrict__ Bm,
    const float* __restrict__ bias, float* __restrict__ out)
{
  __shared__ u16 As[64*64];    // 8 KB
  __shared__ u16 Bs[128*64];   // 16 KB
  const int K = C_;
  int bm = blockIdx.x, bn = blockIdx.y;
  int tid = threadIdx.x;
  int lane = tid & 63, wave = tid >> 6;
  int wcol = wave * 32;
  int qd = lane >> 4, ln = lane & 15;

  f32x4 zero = {0.f, 0.f, 0.f, 0.f};
  f32x4 acc[4][2];
  for (int i = 0; i < 4; i++) for (int j = 0; j < 2; j++) acc[i][j] = zero;

  const u16* Ab = A  + (size_t)bm * 64 * K;
  const u16* Bb = Bm + (size_t)bn * 128 * K;

  for (int k0 = 0; k0 < K; k0 += 64) {
    __syncthreads();
    for (int j = 0; j < 2; j++) {   // A: 512 chunks
      int slot = (wave*2 + j)*64 + lane;
      int r = slot >> 3, kc = slot & 7;
      int c = (kc ^ (r & 7)) * 8;
      async16(&Ab[(size_t)r * K + k0 + c], &As[(wave*2 + j) * 512]);
    }
    for (int j = 0; j < 4; j++) {   // B: 1024 chunks
      int slot = (wave*4 + j)*64 + lane;
      int r = slot >> 3, kc = slot & 7;
      int c = (kc ^ (r & 7)) * 8;
      async16(&Bb[(size_t)r * K + k0 + c], &Bs[(wave*4 + j) * 512]);
    }
    __syncthreads();
    for (int kk2 = 0; kk2 < 2; kk2++) {
      bf16x8 af[4], bfr[2];
      for (int mi = 0; mi < 4; mi++) {
        int row = mi*16 + ln;
        af[mi] = *(const bf16x8*)&As[(row*8 + ((kk2*4 + qd) ^ (ln & 7)))*8];
      }
      for (int ni = 0; ni < 2; ni++) {
        int row = wcol + ni*16 + ln;
        bfr[ni] = *(const bf16x8*)&Bs[(row*8 + ((kk2*4 + qd) ^ (ln & 7)))*8];
      }
      for (int mi = 0; mi < 4; mi++)
        for (int ni = 0; ni < 2; ni++)
          acc[mi][ni] = __builtin_amdgcn_mfma_f32_16x16x32_bf16(af[mi], bfr[ni], acc[mi][ni], 0, 0, 0);
    }
  }

  for (int ni = 0; ni < 2; ni++) {
    int col = bn*128 + wcol + ni*16 + ln;
    float bv = bias[col];
    for (int mi = 0; mi < 4; mi++)
      for (int r = 0; r < 4; r++) {
        int row = bm*64 + mi*16 + qd*4 + r;
        out[(size_t)row * C_ + col] = acc[mi][ni][r] + bv;
      }
  }
}

extern "C" void kernel_launch(void* const* d_in, const int* in_sizes, int n_in,
                              void* d_out, int out_size, void* d_ws, size_t ws_size,
                              hipStream_t stream) {
  const float* x     = (const float*)d_in[0];
  const float* w_qkv = (const float*)d_in[1];
  const float* b_qkv = (const float*)d_in[2];
  const float* w_out = (const float*)d_in[3];
  const float* b_out = (const float*)d_in[4];
  float* out = (float*)d_out;

  char* ws = (char*)d_ws;
  u16* x_bf    = (u16*)(ws);
  u16* wqkv_bf = (u16*)(ws + (size_t)8*1024*1024);
  u16* wout_bf = (u16*)(ws + (size_t)14*1024*1024);
  u16* q_bf    = (u16*)(ws + (size_t)16*1024*1024);  // [B,H,N,D], pre-scaled
  u16* k_bf    = (u16*)(ws + (size_t)24*1024*1024);  // blocked, rows permuted
  u16* v_bf    = (u16*)(ws + (size_t)32*1024*1024);  // [b,h,d,N], chunks XOR-swizzled
  u16* a_bf    = (u16*)(ws + (size_t)40*1024*1024);  // [M][C]

  k_cvt<<<8192, 256, 0, stream>>>(x, w_qkv, w_out, x_bf, wqkv_bf, wout_bf);
  k_gemm_qkv<<<dim3(32, 24), 256, 0, stream>>>(x_bf, wqkv_bf, b_qkv, q_bf, k_bf, v_bf);
  k_attn<<<512, 256, 0, stream>>>(q_bf, k_bf, v_bf, a_bf);
  k_gemm_out<<<dim3(64, 8), 256, 0, stream>>>(a_bf, wout_bf, b_out, out);
}